// Round 1
// baseline (247.237 us; speedup 1.0000x reference)
//
#include <hip/hip_runtime.h>
#include <hip/hip_fp16.h>

#define N_NODES 65536
#define N_EDGES 1048576
#define F_IN    16
#define H       64
#define N_GRAPHS 32
#define NPG     2048
#define OUT_F   12
#define KPG     (NPG * H)   // 131072 per-graph K for FC
#define CAP     4864        // padded per-bucket capacity: mean 4096, sigma 64, +12 sigma
#define NPB     32          // nodes per block in fused agg+gemm kernels

// ================================================================ CSR build
// Edges pack into uint32: src (16b) | dst (16b) << 16.
// Bucket = dst>>8 (256 buckets of 256 nodes), FIXED padded regions of CAP edges.
// No global count+scan passes: gCursor[b] starts at b*CAP; binA allocates within
// the region; binB recovers the actual count from the final cursor value.

// 1 tiny block: init cursors to padded bucket bases; bias-init out
__global__ __launch_bounds__(256) void init_kernel(int* __restrict__ gCursor,
                                                   const float* __restrict__ bfc,
                                                   float* __restrict__ out) {
    int t = threadIdx.x;
    gCursor[t] = t * CAP;
    for (int i = t; i < N_GRAPHS * OUT_F; i += 256) out[i] = bfc[i % OUT_F];
}

// 256 blocks x 4096 edges: LDS-staged bin by dst>>8, coalesced flush into bucket regions
__global__ __launch_bounds__(256) void binA_kernel(const int* __restrict__ src,
                                                   const int* __restrict__ dst,
                                                   int* __restrict__ gCursor,
                                                   unsigned int* __restrict__ binned) {
    __shared__ int hist[256];
    __shared__ int sc[256];
    __shared__ int bnd[257];
    __shared__ int lcur[256];
    __shared__ int blkBase[256];
    __shared__ unsigned int staged[4096];
    int t = threadIdx.x;
    hist[t] = 0; lcur[t] = 0;
    __syncthreads();
    int e0 = blockIdx.x * 4096;
    unsigned int rec[16];
#pragma unroll
    for (int i = 0; i < 16; i++) {
        int e = e0 + i * 256 + t;
        unsigned int s = (unsigned int)src[e];
        unsigned int d = (unsigned int)dst[e];
        rec[i] = s | (d << 16);
        atomicAdd(&hist[d >> 8], 1);
    }
    __syncthreads();
    int cnt = hist[t];
    if (cnt) blkBase[t] = atomicAdd(&gCursor[t], cnt);
    sc[t] = cnt;
    __syncthreads();
    for (int off = 1; off < 256; off <<= 1) {
        int v = (t >= off) ? sc[t - off] : 0;
        __syncthreads();
        sc[t] += v;
        __syncthreads();
    }
    bnd[t] = sc[t] - cnt;
    if (t == 255) bnd[256] = 4096;
    __syncthreads();
#pragma unroll
    for (int i = 0; i < 16; i++) {
        int b = rec[i] >> 24;
        int p = bnd[b] + atomicAdd(&lcur[b], 1);
        staged[p] = rec[i];
    }
    __syncthreads();
    for (int i = t; i < 4096; i += 256) {
        int lo = 0;
#pragma unroll
        for (int s = 128; s > 0; s >>= 1)
            if (bnd[lo + s] <= i) lo += s;
        binned[blkBase[lo] + (i - bnd[lo])] = staged[i];
    }
}

// block per bucket: counting sort -> nbr (ushort), rowinfo{start,cnt}, dinv; fused g1h write
__global__ __launch_bounds__(256) void binB_g1_kernel(const unsigned int* __restrict__ binned,
                                                      const int* __restrict__ gCursor,
                                                      const float* __restrict__ x,
                                                      int2* __restrict__ rowinfo,
                                                      float* __restrict__ dinv,
                                                      unsigned short* __restrict__ nbr,
                                                      __half2* __restrict__ g1h) {
    __shared__ int hist[256];
    __shared__ int sc[256];
    __shared__ int off[256];
    __shared__ int cur[256];
    __shared__ unsigned short outS[8192];
    int b = blockIdx.x, t = threadIdx.x;
    int base = b * CAP;
    int cnt  = gCursor[b] - base;   // actual edges in this bucket after binA
    hist[t] = 0; cur[t] = 0;
    __syncthreads();
    for (int i = t; i < cnt; i += 256) {
        unsigned int r = binned[base + i];
        atomicAdd(&hist[(r >> 16) & 255], 1);
    }
    __syncthreads();
    int c = hist[t];
    sc[t] = c;
    __syncthreads();
    for (int o = 1; o < 256; o <<= 1) {
        int v = (t >= o) ? sc[t - o] : 0;
        __syncthreads();
        sc[t] += v;
        __syncthreads();
    }
    off[t] = sc[t] - c;
    int nd = (b << 8) + t;
    float dv = rsqrtf((float)(c + 1));
    rowinfo[nd] = make_int2(base + sc[t] - c, c);
    dinv[nd]    = dv;
    {
        const float4* xr = (const float4*)(x + (size_t)nd * F_IN);
        float4 x0 = xr[0], x1 = xr[1], x2 = xr[2], x3 = xr[3];
        __half2* gr = g1h + nd * 8;
        gr[0] = __floats2half2_rn(x0.x * dv, x0.y * dv);
        gr[1] = __floats2half2_rn(x0.z * dv, x0.w * dv);
        gr[2] = __floats2half2_rn(x1.x * dv, x1.y * dv);
        gr[3] = __floats2half2_rn(x1.z * dv, x1.w * dv);
        gr[4] = __floats2half2_rn(x2.x * dv, x2.y * dv);
        gr[5] = __floats2half2_rn(x2.z * dv, x2.w * dv);
        gr[6] = __floats2half2_rn(x3.x * dv, x3.y * dv);
        gr[7] = __floats2half2_rn(x3.z * dv, x3.w * dv);
    }
    __syncthreads();
    for (int i = t; i < cnt; i += 256) {
        unsigned int r = binned[base + i];
        int n = (r >> 16) & 255;
        int p = off[n] + atomicAdd(&cur[n], 1);
        outS[p] = (unsigned short)(r & 0xFFFF);
    }
    __syncthreads();
    for (int i = t; i < cnt; i += 256) nbr[base + i] = outS[i];
}

// ================================================================ layer 1 (fused agg + gemm)
// wave per node; after the xor-butterfly EVERY lane holds the reduced sum for its
// feature-pair, so the 16xH GEMM runs in-wave via 8 shfl broadcasts. a1 never
// touches global memory. 2048 blocks x 32 nodes amortize the W1 LDS load.
__global__ __launch_bounds__(256) void agg1_gemm1_kernel(const __half2* __restrict__ g1h,
                                                         const int2* __restrict__ rowinfo,
                                                         const unsigned short* __restrict__ nbr,
                                                         const float* __restrict__ dinv,
                                                         const float* __restrict__ W1,
                                                         const float* __restrict__ b1,
                                                         __half* __restrict__ g2h) {
    __shared__ float Ws[F_IN * H];
    __shared__ float bs[H];
    int t = threadIdx.x;
    for (int i = t; i < F_IN * H; i += 256) Ws[i] = W1[i];
    if (t < H) bs[t] = b1[t];
    __syncthreads();
    int lane = t & 63;
    int w    = t >> 6;
    int f2   = lane & 7;
    int sub  = lane >> 3;
    int v0   = blockIdx.x * NPB;
#pragma unroll 1
    for (int it = 0; it < NPB / 4; ++it) {
        int v = v0 + (it << 2) + w;
        int2 ri = rowinfo[v];
        int r0 = ri.x, r1 = ri.x + ri.y;
        float ax = 0.f, ay = 0.f;
        for (int base = r0; base < r1; base += 64) {
            int er = min(64, r1 - base);
            int nb = (int)nbr[base + lane];
            int j = 0;
            for (; j + 16 <= er; j += 16) {
                int u0 = __shfl(nb, j + sub, 64);
                int u1 = __shfl(nb, j + 8 + sub, 64);
                float2 x0 = __half22float2(g1h[(u0 << 3) + f2]);
                float2 x1 = __half22float2(g1h[(u1 << 3) + f2]);
                ax += x0.x + x1.x;
                ay += x0.y + x1.y;
            }
            for (; j < er; j += 8) {
                int idx = j + sub;
                int u = __shfl(nb, idx < er ? idx : 0, 64);
                float2 xv = __half22float2(g1h[(u << 3) + f2]);
                if (idx < er) { ax += xv.x; ay += xv.y; }
            }
        }
        ax += __shfl_xor(ax, 8, 64);  ax += __shfl_xor(ax, 16, 64);  ax += __shfl_xor(ax, 32, 64);
        ay += __shfl_xor(ay, 8, 64);  ay += __shfl_xor(ay, 16, 64);  ay += __shfl_xor(ay, 32, 64);
        float2 sv = __half22float2(g1h[(v << 3) + f2]);
        float dv = dinv[v];
        ax = dv * (ax + sv.x);
        ay = dv * (ay + sv.y);
        // in-wave GEMM: a1 pairs live at lanes 0..7 (f2 == lane)
        float s = bs[lane];
#pragma unroll
        for (int k2 = 0; k2 < 8; ++k2) {
            float bx = __shfl(ax, k2, 64);
            float by = __shfl(ay, k2, 64);
            s += bx * Ws[(2 * k2) * H + lane] + by * Ws[(2 * k2 + 1) * H + lane];
        }
        g2h[(v << 6) + lane] = __float2half(dv * tanhf(s));
    }
}

// ================================================================ layer 2 (fused agg + gemm)
__global__ __launch_bounds__(256) void agg2_gemm2_kernel(const __half2* __restrict__ g2h,
                                                         const int2* __restrict__ rowinfo,
                                                         const unsigned short* __restrict__ nbr,
                                                         const float* __restrict__ dinv,
                                                         const float* __restrict__ W2,
                                                         const float* __restrict__ b2,
                                                         float* __restrict__ h2) {
    __shared__ float Ws[H * H];   // 16 KB
    __shared__ float bs[H];
    int t = threadIdx.x;
    for (int i = t; i < H * H; i += 256) Ws[i] = W2[i];
    if (t < H) bs[t] = b2[t];
    __syncthreads();
    int lane = t & 63;
    int w    = t >> 6;
    int f2   = lane & 31;
    int sub  = lane >> 5;
    int v0   = blockIdx.x * NPB;
#pragma unroll 1
    for (int it = 0; it < NPB / 4; ++it) {
        int v = v0 + (it << 2) + w;
        int2 ri = rowinfo[v];
        int r0 = ri.x, r1 = ri.x + ri.y;
        float ax = 0.f, ay = 0.f;
        for (int base = r0; base < r1; base += 64) {
            int er = min(64, r1 - base);
            int nb = (int)nbr[base + lane];
            int j = 0;
            for (; j + 8 <= er; j += 8) {
                int u0 = __shfl(nb, j + sub, 64);
                int u1 = __shfl(nb, j + 2 + sub, 64);
                int u2 = __shfl(nb, j + 4 + sub, 64);
                int u3 = __shfl(nb, j + 6 + sub, 64);
                float2 x0 = __half22float2(g2h[(u0 << 5) + f2]);
                float2 x1 = __half22float2(g2h[(u1 << 5) + f2]);
                float2 x2 = __half22float2(g2h[(u2 << 5) + f2]);
                float2 x3 = __half22float2(g2h[(u3 << 5) + f2]);
                ax += (x0.x + x1.x) + (x2.x + x3.x);
                ay += (x0.y + x1.y) + (x2.y + x3.y);
            }
            for (; j < er; j += 2) {
                int idx = j + sub;
                int u = __shfl(nb, idx < er ? idx : 0, 64);
                float2 xv = __half22float2(g2h[(u << 5) + f2]);
                if (idx < er) { ax += xv.x; ay += xv.y; }
            }
        }
        ax += __shfl_xor(ax, 32, 64);
        ay += __shfl_xor(ay, 32, 64);
        float2 sv = __half22float2(g2h[(v << 5) + f2]);
        float dv = dinv[v];
        ax = dv * (ax + sv.x);
        ay = dv * (ay + sv.y);
        // in-wave GEMM: a2 pairs live at lanes 0..31 (f2 == lane)
        float s = bs[lane];
#pragma unroll
        for (int k2 = 0; k2 < 32; ++k2) {
            float bx = __shfl(ax, k2, 64);
            float by = __shfl(ay, k2, 64);
            s += bx * Ws[(2 * k2) * H + lane] + by * Ws[(2 * k2 + 1) * H + lane];
        }
        h2[(v << 6) + lane] = tanhf(s);
    }
}

// ================================================================ FC head
// grid: 128 kchunks (1024 k) x 4 graph-groups (8 graphs) = 512 blocks x 256 thr.
__global__ __launch_bounds__(256) void fc_kernel(const float* __restrict__ h2,
                                                 const float* __restrict__ Wfc,
                                                 float* __restrict__ out) {
    int kc = blockIdx.x & 127;
    int gg = blockIdx.x >> 7;
    int t  = threadIdx.x;
    float acc[8][12];
#pragma unroll
    for (int g = 0; g < 8; g++)
#pragma unroll
        for (int j = 0; j < OUT_F; j++) acc[g][j] = 0.f;
    const float* hbase = h2 + (size_t)gg * 8 * KPG;
#pragma unroll
    for (int i = 0; i < 4; i++) {
        int k = (kc << 10) + (i << 8) + t;
        const float4* w4 = (const float4*)(Wfc + (size_t)k * OUT_F);
        float4 w0 = w4[0], w1 = w4[1], w2 = w4[2];
        float hv[8];
#pragma unroll
        for (int g = 0; g < 8; g++) hv[g] = hbase[(size_t)g * KPG + k];
#pragma unroll
        for (int g = 0; g < 8; g++) {
            acc[g][0] += hv[g] * w0.x;  acc[g][1] += hv[g] * w0.y;
            acc[g][2] += hv[g] * w0.z;  acc[g][3] += hv[g] * w0.w;
            acc[g][4] += hv[g] * w1.x;  acc[g][5] += hv[g] * w1.y;
            acc[g][6] += hv[g] * w1.z;  acc[g][7] += hv[g] * w1.w;
            acc[g][8] += hv[g] * w2.x;  acc[g][9] += hv[g] * w2.y;
            acc[g][10] += hv[g] * w2.z; acc[g][11] += hv[g] * w2.w;
        }
    }
#pragma unroll
    for (int g = 0; g < 8; g++)
#pragma unroll
        for (int j = 0; j < OUT_F; j++) {
            float v = acc[g][j];
            v += __shfl_xor(v, 1, 64);  v += __shfl_xor(v, 2, 64);
            v += __shfl_xor(v, 4, 64);  v += __shfl_xor(v, 8, 64);
            v += __shfl_xor(v, 16, 64); v += __shfl_xor(v, 32, 64);
            acc[g][j] = v;
        }
    __shared__ float red[4][96];
    int w = t >> 6;
    if ((t & 63) == 0) {
#pragma unroll
        for (int g = 0; g < 8; g++)
#pragma unroll
            for (int j = 0; j < OUT_F; j++) red[w][g * OUT_F + j] = acc[g][j];
    }
    __syncthreads();
    if (t < 96)
        atomicAdd(&out[gg * 96 + t], red[0][t] + red[1][t] + red[2][t] + red[3][t]);
}

// ================================================================ launcher
extern "C" void kernel_launch(void* const* d_in, const int* in_sizes, int n_in,
                              void* d_out, int out_size, void* d_ws, size_t ws_size,
                              hipStream_t stream) {
    const float* x    = (const float*)d_in[0];
    const int*   edge = (const int*)d_in[1];
    const int*   src  = edge;
    const int*   dst  = edge + N_EDGES;
    const float* W1  = (const float*)d_in[3];
    const float* b1  = (const float*)d_in[4];
    const float* W2  = (const float*)d_in[5];
    const float* b2  = (const float*)d_in[6];
    const float* Wfc = (const float*)d_in[7];
    const float* bfc = (const float*)d_in[8];
    float* out = (float*)d_out;

    char* p = (char*)d_ws;
    auto alloc = [&](size_t n) { char* r = p; p += (n + 255) & ~(size_t)255; return r; };
    int*   gCursor    = (int*)alloc(256 * 4);
    int2*  rowinfo    = (int2*)alloc((size_t)N_NODES * 8);
    float* dinv       = (float*)alloc(N_NODES * 4);
    unsigned short* nbr = (unsigned short*)alloc((size_t)256 * CAP * 2 + 256); // pad: agg reads up to +63
    __half* g1h       = (__half*)alloc((size_t)N_NODES * F_IN * 2);
    __half* g2h       = (__half*)alloc((size_t)N_NODES * H * 2);
    float* h2         = (float*)alloc((size_t)N_NODES * H * 4);
    unsigned int* binned = (unsigned int*)alloc((size_t)256 * CAP * 4);

    init_kernel<<<1, 256, 0, stream>>>(gCursor, bfc, out);
    binA_kernel<<<256, 256, 0, stream>>>(src, dst, gCursor, binned);
    binB_g1_kernel<<<256, 256, 0, stream>>>(binned, gCursor, x, rowinfo, dinv, nbr,
                                            (__half2*)g1h);
    agg1_gemm1_kernel<<<N_NODES / NPB, 256, 0, stream>>>((const __half2*)g1h, rowinfo, nbr,
                                                         dinv, W1, b1, g2h);
    agg2_gemm2_kernel<<<N_NODES / NPB, 256, 0, stream>>>((const __half2*)g2h, rowinfo, nbr,
                                                         dinv, W2, b2, h2);
    fc_kernel<<<512, 256, 0, stream>>>(h2, Wfc, out);
}

// Round 2
// 231.733 us; speedup vs baseline: 1.0669x; 1.0669x over previous
//
#include <hip/hip_runtime.h>
#include <hip/hip_fp16.h>

#define N_NODES 65536
#define N_EDGES 1048576
#define F_IN    16
#define H       64
#define N_GRAPHS 32
#define NPG     2048
#define OUT_F   12
#define KPG     (NPG * H)   // 131072 per-graph K for FC
#define CAP     4864        // padded per-bucket capacity: mean 4096, sigma 64, +12 sigma
#define NPB     16          // nodes per block in fused agg+gemm kernels

// ================================================================ CSR build
// Edges pack into uint32: src (16b) | dst (16b) << 16.
// Bucket = dst>>8 (256 buckets of 256 nodes), FIXED padded regions of CAP edges.

// 1 tiny block: init cursors to padded bucket bases; bias-init out
__global__ __launch_bounds__(256) void init_kernel(int* __restrict__ gCursor,
                                                   const float* __restrict__ bfc,
                                                   float* __restrict__ out) {
    int t = threadIdx.x;
    gCursor[t] = t * CAP;
    for (int i = t; i < N_GRAPHS * OUT_F; i += 256) out[i] = bfc[i % OUT_F];
}

// 256 blocks x 4096 edges: LDS-staged bin by dst>>8, coalesced flush into bucket regions
__global__ __launch_bounds__(256) void binA_kernel(const int* __restrict__ src,
                                                   const int* __restrict__ dst,
                                                   int* __restrict__ gCursor,
                                                   unsigned int* __restrict__ binned) {
    __shared__ int hist[256];
    __shared__ int sc[256];
    __shared__ int bnd[257];
    __shared__ int lcur[256];
    __shared__ int blkBase[256];
    __shared__ unsigned int staged[4096];
    int t = threadIdx.x;
    hist[t] = 0; lcur[t] = 0;
    __syncthreads();
    int e0 = blockIdx.x * 4096;
    unsigned int rec[16];
#pragma unroll
    for (int i = 0; i < 16; i++) {
        int e = e0 + i * 256 + t;
        unsigned int s = (unsigned int)src[e];
        unsigned int d = (unsigned int)dst[e];
        rec[i] = s | (d << 16);
        atomicAdd(&hist[d >> 8], 1);
    }
    __syncthreads();
    int cnt = hist[t];
    if (cnt) blkBase[t] = atomicAdd(&gCursor[t], cnt);
    sc[t] = cnt;
    __syncthreads();
    for (int off = 1; off < 256; off <<= 1) {
        int v = (t >= off) ? sc[t - off] : 0;
        __syncthreads();
        sc[t] += v;
        __syncthreads();
    }
    bnd[t] = sc[t] - cnt;
    if (t == 255) bnd[256] = 4096;
    __syncthreads();
#pragma unroll
    for (int i = 0; i < 16; i++) {
        int b = rec[i] >> 24;
        int p = bnd[b] + atomicAdd(&lcur[b], 1);
        staged[p] = rec[i];
    }
    __syncthreads();
    for (int i = t; i < 4096; i += 256) {
        int lo = 0;
#pragma unroll
        for (int s = 128; s > 0; s >>= 1)
            if (bnd[lo + s] <= i) lo += s;
        binned[blkBase[lo] + (i - bnd[lo])] = staged[i];
    }
}

// block per bucket: counting sort -> nbr (ushort), rowinfo{start,cnt}, dinv; fused g1h write
__global__ __launch_bounds__(256) void binB_g1_kernel(const unsigned int* __restrict__ binned,
                                                      const int* __restrict__ gCursor,
                                                      const float* __restrict__ x,
                                                      int2* __restrict__ rowinfo,
                                                      float* __restrict__ dinv,
                                                      unsigned short* __restrict__ nbr,
                                                      __half2* __restrict__ g1h) {
    __shared__ int hist[256];
    __shared__ int sc[256];
    __shared__ int off[256];
    __shared__ int cur[256];
    __shared__ unsigned short outS[8192];
    int b = blockIdx.x, t = threadIdx.x;
    int base = b * CAP;
    int cnt  = gCursor[b] - base;   // actual edges in this bucket after binA
    hist[t] = 0; cur[t] = 0;
    __syncthreads();
    for (int i = t; i < cnt; i += 256) {
        unsigned int r = binned[base + i];
        atomicAdd(&hist[(r >> 16) & 255], 1);
    }
    __syncthreads();
    int c = hist[t];
    sc[t] = c;
    __syncthreads();
    for (int o = 1; o < 256; o <<= 1) {
        int v = (t >= o) ? sc[t - o] : 0;
        __syncthreads();
        sc[t] += v;
        __syncthreads();
    }
    off[t] = sc[t] - c;
    int nd = (b << 8) + t;
    float dv = rsqrtf((float)(c + 1));
    rowinfo[nd] = make_int2(base + sc[t] - c, c);
    dinv[nd]    = dv;
    {
        const float4* xr = (const float4*)(x + (size_t)nd * F_IN);
        float4 x0 = xr[0], x1 = xr[1], x2 = xr[2], x3 = xr[3];
        __half2* gr = g1h + nd * 8;
        gr[0] = __floats2half2_rn(x0.x * dv, x0.y * dv);
        gr[1] = __floats2half2_rn(x0.z * dv, x0.w * dv);
        gr[2] = __floats2half2_rn(x1.x * dv, x1.y * dv);
        gr[3] = __floats2half2_rn(x1.z * dv, x1.w * dv);
        gr[4] = __floats2half2_rn(x2.x * dv, x2.y * dv);
        gr[5] = __floats2half2_rn(x2.z * dv, x2.w * dv);
        gr[6] = __floats2half2_rn(x3.x * dv, x3.y * dv);
        gr[7] = __floats2half2_rn(x3.z * dv, x3.w * dv);
    }
    __syncthreads();
    for (int i = t; i < cnt; i += 256) {
        unsigned int r = binned[base + i];
        int n = (r >> 16) & 255;
        int p = off[n] + atomicAdd(&cur[n], 1);
        outS[p] = (unsigned short)(r & 0xFFFF);
    }
    __syncthreads();
    for (int i = t; i < cnt; i += 256) nbr[base + i] = outS[i];
}

// ---------------------------------------------------------------- unpack helpers
__device__ __forceinline__ void add8(float* acc, float4 q) {
    union { float4 f; __half2 h[4]; } u; u.f = q;
#pragma unroll
    for (int c = 0; c < 4; c++) {
        float2 p = __half22float2(u.h[c]);
        acc[2 * c]     += p.x;
        acc[2 * c + 1] += p.y;
    }
}
__device__ __forceinline__ void add4(float* acc, float2 q) {
    union { float2 f; __half2 h[2]; } u; u.f = q;
    float2 p0 = __half22float2(u.h[0]);
    float2 p1 = __half22float2(u.h[1]);
    acc[0] += p0.x; acc[1] += p0.y; acc[2] += p1.x; acc[3] += p1.y;
}

// ================================================================ layer 1 (fused agg + gemm)
// Wide-gather layout: g1 row = 32B = 4 x float2. Each lane owns an 8B chunk
// (f4 = lane&3 -> features 4*f4..4*f4+3); sub = lane>>2 gives 16 u-slots per
// wave-iteration. One float2 VMEM op per 16 edges per lane (vs 2x4B before).
__global__ __launch_bounds__(256) void agg1_gemm1_kernel(const __half2* __restrict__ g1h,
                                                         const int2* __restrict__ rowinfo,
                                                         const unsigned short* __restrict__ nbr,
                                                         const float* __restrict__ dinv,
                                                         const float* __restrict__ W1,
                                                         const float* __restrict__ b1,
                                                         __half* __restrict__ g2h) {
    const float2* g1v = (const float2*)g1h;   // row = 4 float2
    __shared__ float Ws[F_IN * H];
    __shared__ float bs[H];
    int t = threadIdx.x;
    for (int i = t; i < F_IN * H; i += 256) Ws[i] = W1[i];
    if (t < H) bs[t] = b1[t];
    __syncthreads();
    int lane = t & 63;
    int w    = t >> 6;
    int f4   = lane & 3;
    int sub  = lane >> 2;
    int v0   = blockIdx.x * NPB;
#pragma unroll 1
    for (int it = 0; it < NPB / 4; ++it) {
        int v = v0 + (it << 2) + w;
        int2 ri = rowinfo[v];
        int r0 = ri.x, r1 = ri.x + ri.y;
        float acc[4] = {0.f, 0.f, 0.f, 0.f};
        for (int base = r0; base < r1; base += 64) {
            int er = min(64, r1 - base);
            int nb = (int)nbr[base + lane];
            int j = 0;
            for (; j + 32 <= er; j += 32) {
                int u0 = __shfl(nb, j + sub, 64);
                int u1 = __shfl(nb, j + 16 + sub, 64);
                float2 q0 = g1v[(u0 << 2) + f4];
                float2 q1 = g1v[(u1 << 2) + f4];
                add4(acc, q0);
                add4(acc, q1);
            }
            for (; j < er; j += 16) {
                int idx = j + sub;
                int u = __shfl(nb, idx < er ? idx : 0, 64);
                float2 q = g1v[(u << 2) + f4];
                if (idx < er) add4(acc, q);
            }
        }
#pragma unroll
        for (int i = 0; i < 4; i++) {
            acc[i] += __shfl_xor(acc[i], 4, 64);
            acc[i] += __shfl_xor(acc[i], 8, 64);
            acc[i] += __shfl_xor(acc[i], 16, 64);
            acc[i] += __shfl_xor(acc[i], 32, 64);
        }
        float selfq[4];
        {
            float2 sq = g1v[(v << 2) + f4];
            selfq[0] = selfq[1] = selfq[2] = selfq[3] = 0.f;
            add4(selfq, sq);
        }
        float dv = dinv[v];
#pragma unroll
        for (int i = 0; i < 4; i++) acc[i] = dv * (acc[i] + selfq[i]);
        // in-wave GEMM: feature k lives at lane (k>>2), component (k&3)
        float s = bs[lane];
#pragma unroll
        for (int k = 0; k < F_IN; ++k) {
            float bk = __shfl(acc[k & 3], k >> 2, 64);
            s += bk * Ws[k * H + lane];
        }
        g2h[(v << 6) + lane] = __float2half(dv * tanhf(s));
    }
}

// ================================================================ layer 2 (fused agg + gemm)
// g2 row = 128B = 8 x float4. Each lane owns a 16B chunk (f8 = lane&7 ->
// features 8*f8..8*f8+7); sub = lane>>3 gives 8 u-slots per iteration.
// One float4 VMEM op per 8 edges per lane (vs 4x4B before) -> 4x fewer VMEM
// instructions, 4x more bytes in flight per outstanding load.
__global__ __launch_bounds__(256) void agg2_gemm2_kernel(const __half2* __restrict__ g2h,
                                                         const int2* __restrict__ rowinfo,
                                                         const unsigned short* __restrict__ nbr,
                                                         const float* __restrict__ dinv,
                                                         const float* __restrict__ W2,
                                                         const float* __restrict__ b2,
                                                         float* __restrict__ h2) {
    const float4* g2v = (const float4*)g2h;   // row = 8 float4
    __shared__ float Ws[H * H];   // 16 KB
    __shared__ float bs[H];
    int t = threadIdx.x;
    for (int i = t; i < H * H; i += 256) Ws[i] = W2[i];
    if (t < H) bs[t] = b2[t];
    __syncthreads();
    int lane = t & 63;
    int w    = t >> 6;
    int f8   = lane & 7;
    int sub  = lane >> 3;
    int v0   = blockIdx.x * NPB;
#pragma unroll 1
    for (int it = 0; it < NPB / 4; ++it) {
        int v = v0 + (it << 2) + w;
        int2 ri = rowinfo[v];
        int r0 = ri.x, r1 = ri.x + ri.y;
        float acc[8] = {0.f, 0.f, 0.f, 0.f, 0.f, 0.f, 0.f, 0.f};
        for (int base = r0; base < r1; base += 64) {
            int er = min(64, r1 - base);
            int nb = (int)nbr[base + lane];
            int j = 0;
            for (; j + 16 <= er; j += 16) {
                int u0 = __shfl(nb, j + sub, 64);
                int u1 = __shfl(nb, j + 8 + sub, 64);
                float4 q0 = g2v[(u0 << 3) + f8];
                float4 q1 = g2v[(u1 << 3) + f8];
                add8(acc, q0);
                add8(acc, q1);
            }
            for (; j < er; j += 8) {
                int idx = j + sub;
                int u = __shfl(nb, idx < er ? idx : 0, 64);
                float4 q = g2v[(u << 3) + f8];
                if (idx < er) add8(acc, q);
            }
        }
#pragma unroll
        for (int i = 0; i < 8; i++) {
            acc[i] += __shfl_xor(acc[i], 8, 64);
            acc[i] += __shfl_xor(acc[i], 16, 64);
            acc[i] += __shfl_xor(acc[i], 32, 64);
        }
        float selfq[8];
        {
            float4 sq = g2v[(v << 3) + f8];
#pragma unroll
            for (int i = 0; i < 8; i++) selfq[i] = 0.f;
            add8(selfq, sq);
        }
        float dv = dinv[v];
#pragma unroll
        for (int i = 0; i < 8; i++) acc[i] = dv * (acc[i] + selfq[i]);
        // in-wave GEMM: feature k lives at lane (k>>3), component (k&7)
        float s = bs[lane];
#pragma unroll
        for (int k = 0; k < H; ++k) {
            float bk = __shfl(acc[k & 7], k >> 3, 64);
            s += bk * Ws[k * H + lane];
        }
        h2[(v << 6) + lane] = tanhf(s);
    }
}

// ================================================================ FC head
// grid: 128 kchunks (1024 k) x 4 graph-groups (8 graphs) = 512 blocks x 256 thr.
__global__ __launch_bounds__(256) void fc_kernel(const float* __restrict__ h2,
                                                 const float* __restrict__ Wfc,
                                                 float* __restrict__ out) {
    int kc = blockIdx.x & 127;
    int gg = blockIdx.x >> 7;
    int t  = threadIdx.x;
    float acc[8][12];
#pragma unroll
    for (int g = 0; g < 8; g++)
#pragma unroll
        for (int j = 0; j < OUT_F; j++) acc[g][j] = 0.f;
    const float* hbase = h2 + (size_t)gg * 8 * KPG;
#pragma unroll
    for (int i = 0; i < 4; i++) {
        int k = (kc << 10) + (i << 8) + t;
        const float4* w4 = (const float4*)(Wfc + (size_t)k * OUT_F);
        float4 w0 = w4[0], w1 = w4[1], w2 = w4[2];
        float hv[8];
#pragma unroll
        for (int g = 0; g < 8; g++) hv[g] = hbase[(size_t)g * KPG + k];
#pragma unroll
        for (int g = 0; g < 8; g++) {
            acc[g][0] += hv[g] * w0.x;  acc[g][1] += hv[g] * w0.y;
            acc[g][2] += hv[g] * w0.z;  acc[g][3] += hv[g] * w0.w;
            acc[g][4] += hv[g] * w1.x;  acc[g][5] += hv[g] * w1.y;
            acc[g][6] += hv[g] * w1.z;  acc[g][7] += hv[g] * w1.w;
            acc[g][8] += hv[g] * w2.x;  acc[g][9] += hv[g] * w2.y;
            acc[g][10] += hv[g] * w2.z; acc[g][11] += hv[g] * w2.w;
        }
    }
#pragma unroll
    for (int g = 0; g < 8; g++)
#pragma unroll
        for (int j = 0; j < OUT_F; j++) {
            float v = acc[g][j];
            v += __shfl_xor(v, 1, 64);  v += __shfl_xor(v, 2, 64);
            v += __shfl_xor(v, 4, 64);  v += __shfl_xor(v, 8, 64);
            v += __shfl_xor(v, 16, 64); v += __shfl_xor(v, 32, 64);
            acc[g][j] = v;
        }
    __shared__ float red[4][96];
    int w = t >> 6;
    if ((t & 63) == 0) {
#pragma unroll
        for (int g = 0; g < 8; g++)
#pragma unroll
            for (int j = 0; j < OUT_F; j++) red[w][g * OUT_F + j] = acc[g][j];
    }
    __syncthreads();
    if (t < 96)
        atomicAdd(&out[gg * 96 + t], red[0][t] + red[1][t] + red[2][t] + red[3][t]);
}

// ================================================================ launcher
extern "C" void kernel_launch(void* const* d_in, const int* in_sizes, int n_in,
                              void* d_out, int out_size, void* d_ws, size_t ws_size,
                              hipStream_t stream) {
    const float* x    = (const float*)d_in[0];
    const int*   edge = (const int*)d_in[1];
    const int*   src  = edge;
    const int*   dst  = edge + N_EDGES;
    const float* W1  = (const float*)d_in[3];
    const float* b1  = (const float*)d_in[4];
    const float* W2  = (const float*)d_in[5];
    const float* b2  = (const float*)d_in[6];
    const float* Wfc = (const float*)d_in[7];
    const float* bfc = (const float*)d_in[8];
    float* out = (float*)d_out;

    char* p = (char*)d_ws;
    auto alloc = [&](size_t n) { char* r = p; p += (n + 255) & ~(size_t)255; return r; };
    int*   gCursor    = (int*)alloc(256 * 4);
    int2*  rowinfo    = (int2*)alloc((size_t)N_NODES * 8);
    float* dinv       = (float*)alloc(N_NODES * 4);
    unsigned short* nbr = (unsigned short*)alloc((size_t)256 * CAP * 2 + 256); // pad: agg reads up to +63
    __half* g1h       = (__half*)alloc((size_t)N_NODES * F_IN * 2);
    __half* g2h       = (__half*)alloc((size_t)N_NODES * H * 2);
    float* h2         = (float*)alloc((size_t)N_NODES * H * 4);
    unsigned int* binned = (unsigned int*)alloc((size_t)256 * CAP * 4);

    init_kernel<<<1, 256, 0, stream>>>(gCursor, bfc, out);
    binA_kernel<<<256, 256, 0, stream>>>(src, dst, gCursor, binned);
    binB_g1_kernel<<<256, 256, 0, stream>>>(binned, gCursor, x, rowinfo, dinv, nbr,
                                            (__half2*)g1h);
    agg1_gemm1_kernel<<<N_NODES / NPB, 256, 0, stream>>>((const __half2*)g1h, rowinfo, nbr,
                                                         dinv, W1, b1, g2h);
    agg2_gemm2_kernel<<<N_NODES / NPB, 256, 0, stream>>>((const __half2*)g2h, rowinfo, nbr,
                                                         dinv, W2, b2, h2);
    fc_kernel<<<512, 256, 0, stream>>>(h2, Wfc, out);
}